// Round 1
// 484.978 us; speedup vs baseline: 1.1299x; 1.1299x over previous
//
#include <hip/hip_runtime.h>
#include <cstdint>
#include <cstddef>

#define T_TOKENS 8192
#define HID 1024
#define HID2 2048
#define NE 8

typedef unsigned short u16;
typedef unsigned int u32;
typedef __bf16 bf16x8 __attribute__((ext_vector_type(8)));
typedef float f32x4 __attribute__((ext_vector_type(4)));

__device__ __forceinline__ float bf2f(u16 u) {
    union { u32 i; float f; } x; x.i = ((u32)u) << 16; return x.f;
}
__device__ __forceinline__ u16 f2bf(float f) {
    union { float f; u32 i; } x; x.f = f;
    u32 r = x.i + 0x7fffu + ((x.i >> 16) & 1u);   // RNE
    return (u16)(r >> 16);
}

// async 16B global -> LDS (lane-ordered dest: base + lane*16)
__device__ __forceinline__ void cp16(const void* g, void* l) {
    __builtin_amdgcn_global_load_lds(
        (const __attribute__((address_space(1))) u32*)g,
        (__attribute__((address_space(3))) u32*)l,
        16, 0, 0);
}

// tanh-approx GELU: |err| < ~3e-4, buried under bf16 rounding
__device__ __forceinline__ float gelu_f(float v) {
    float v2 = v * v;
    float t = fmaf(0.0713548162726f, v2, 1.59576912161f);
    float d = 1.0f + __expf(-v * t);
    return v * __builtin_amdgcn_rcpf(d);
}

// ---------------- router: 8 tokens/wave, fused x->bf16 convert ----------------
__global__ __launch_bounds__(256) void router_kernel(
    const float* __restrict__ x, const float* __restrict__ rw,
    u16* __restrict__ xb,
    int* __restrict__ cnt, int* __restrict__ rowlist,
    int* __restrict__ tok_slots, float* __restrict__ tok_w)
{
    __shared__ int lbin[NE];
    __shared__ int gbase[NE];
    int tid = threadIdx.x;
    if (tid < NE) lbin[tid] = 0;
    __syncthreads();

    int wave = tid >> 6;
    int lane = tid & 63;
    int tg = lane >> 3, il = lane & 7;
    int t = blockIdx.x * 32 + wave * 8 + tg;

    const float* xrow = x + (size_t)t * HID;
    u16* xbrow = xb + (size_t)t * HID;

    float acc[NE];
#pragma unroll
    for (int e = 0; e < NE; e++) acc[e] = 0.f;

#pragma unroll 8
    for (int q = 0; q < 32; q++) {
        int c = il * 4 + 32 * q;
        float4 xv = *(const float4*)(xrow + c);
        u16 p[4] = { f2bf(xv.x), f2bf(xv.y), f2bf(xv.z), f2bf(xv.w) };
        *(uint2*)(xbrow + c) = *(const uint2*)p;
#pragma unroll
        for (int e = 0; e < NE; e++) {
            float4 rv = *(const float4*)(rw + (size_t)e * HID + c);
            acc[e] = fmaf(xv.x, rv.x, acc[e]);
            acc[e] = fmaf(xv.y, rv.y, acc[e]);
            acc[e] = fmaf(xv.z, rv.z, acc[e]);
            acc[e] = fmaf(xv.w, rv.w, acc[e]);
        }
    }
#pragma unroll
    for (int e = 0; e < NE; e++) {
        acc[e] += __shfl_xor(acc[e], 1, 64);
        acc[e] += __shfl_xor(acc[e], 2, 64);
        acc[e] += __shfl_xor(acc[e], 4, 64);
    }

    int i0 = 0, i1 = 0, ph0 = 0, ph1 = 0;
    float w0 = 0.f, w1 = 0.f;
    if (il == 0) {
        float v0 = -1e30f;
#pragma unroll
        for (int e = 0; e < NE; e++) if (acc[e] > v0) { v0 = acc[e]; i0 = e; }
        float v1 = -1e30f;
#pragma unroll
        for (int e = 0; e < NE; e++) if (e != i0 && acc[e] > v1) { v1 = acc[e]; i1 = e; }
        w0 = 1.0f / (1.0f + __expf(v1 - v0));
        w1 = 1.0f - w0;
        ph0 = atomicAdd(&lbin[i0], 1);
        ph1 = atomicAdd(&lbin[i1], 1);
    }
    __syncthreads();
    if (tid < NE) gbase[tid] = atomicAdd(&cnt[tid * 32], lbin[tid]);
    __syncthreads();
    if (il == 0) {
        int p0 = gbase[i0] + ph0;
        int p1 = gbase[i1] + ph1;
        rowlist[i0 * T_TOKENS + p0] = t;
        rowlist[i1 * T_TOKENS + p1] = t;
        tok_slots[t * 2 + 0] = (i0 << 16) | p0;
        tok_slots[t * 2 + 1] = (i1 << 16) | p1;
        tok_w[t * 2 + 0] = w0;
        tok_w[t * 2 + 1] = w1;
    }
}

#define BM 256
#define BN 256
#define BK 64
#define LDSE (BM * BK)   // elements per LDS buffer

// ------- offsets: scan + compact + tile map (skip no-op blocks) -------
__global__ void offsets_kernel(const int* __restrict__ cnt,
                               int* __restrict__ off, int* __restrict__ cntc,
                               int* __restrict__ tmap, int* __restrict__ ntile)
{
    if (threadIdx.x == 0) {
        int s = 0, ti = 0;
        for (int e = 0; e < NE; e++) {
            int c = cnt[e * 32];
            off[e] = s; cntc[e] = c; s += c;
            int nmt = (c + BM - 1) / BM;
            for (int m = 0; m < nmt; m++) tmap[ti++] = (e << 16) | m;
        }
        ntile[0] = ti;
    }
}

// ------- convert+transpose: fp32 [E][K][N] -> bf16 [E][N][K] -------
__global__ __launch_bounds__(256) void convtrans_kernel(
    const float* __restrict__ in, u16* __restrict__ outp, int K, int N)
{
    __shared__ u16 tile[64][72];
    int e = blockIdx.z;
    const float* ip = in + (size_t)e * K * N;
    u16* op = outp + (size_t)e * K * N;
    int n0 = blockIdx.x * 64, k0 = blockIdx.y * 64;
    int t = threadIdx.x;

    int k = t >> 2;
    int nq = (t & 3) * 16;
    const float* src = ip + (size_t)(k0 + k) * N + n0 + nq;
#pragma unroll
    for (int q = 0; q < 4; q++) {
        float4 v = *(const float4*)(src + q * 4);
        tile[nq + q * 4 + 0][k] = f2bf(v.x);
        tile[nq + q * 4 + 1][k] = f2bf(v.y);
        tile[nq + q * 4 + 2][k] = f2bf(v.z);
        tile[nq + q * 4 + 3][k] = f2bf(v.w);
    }
    __syncthreads();

    int n = t >> 2;
    int kq = (t & 3) * 16;
    u16* dst = op + (size_t)(n0 + n) * K + k0 + kq;
    *(uint4*)(dst + 0) = *(const uint4*)&tile[n][kq + 0];
    *(uint4*)(dst + 8) = *(const uint4*)&tile[n][kq + 8];
}

// ---------------- grouped GEMM1: h = gelu(X_gather @ W1t[e]^T) ----------------
// 256x256 tile, BK=64, 8 waves (2M x 4N), double-buffered LDS,
// T3-minimum 2-phase: stage(next) -> compute(cur) -> vmcnt(0)+barrier.
__global__ __launch_bounds__(512, 2) void gemm1_kernel(
    const u16* __restrict__ xb, const u16* __restrict__ w1t,
    const int* __restrict__ cntc, const int* __restrict__ off,
    const int* __restrict__ rowlist, const int* __restrict__ tmap,
    const int* __restrict__ ntile, u16* __restrict__ hbuf)
{
    __shared__ u16 As[2][LDSE];
    __shared__ u16 Bs[2][LDSE];
    __shared__ int toks[BM];

    int bt = blockIdx.x;
    if (bt >= ntile[0]) return;
    int em = tmap[bt];
    int e = em >> 16, mt = em & 0xffff;
    int nt = blockIdx.y;
    int n_e = cntc[e];

    int tid = threadIdx.x;
    if (tid < BM) {
        int r = mt * BM + tid;
        if (r >= n_e) r = n_e - 1;          // clamp: duplicate last valid row
        toks[tid] = rowlist[e * T_TOKENS + r];
    }
    __syncthreads();

    int wv = tid >> 6, lane = tid & 63;
    int wm = (wv >> 2) * 128, wn = (wv & 3) * 64;
    int l15 = lane & 15, l4 = lane >> 4;
    int sr = lane >> 3, sc = lane & 7;

    const u16* w1e = w1t + ((size_t)e * HID2 + nt * BN) * HID;

    const u16* aptr[4]; const u16* bptr[4];
    u16* adst[4]; u16* bdst[4];
#pragma unroll
    for (int i = 0; i < 4; i++) {
        int m = wv * 32 + i * 8 + sr;
        int gq = sc ^ (m & 7);
        aptr[i] = xb + (size_t)toks[m] * HID + gq * 8;
        adst[i] = &As[0][m * BK + sc * 8];
        bptr[i] = w1e + (size_t)m * HID + gq * 8;
        bdst[i] = &Bs[0][m * BK + sc * 8];
    }

    f32x4 acc[8][4];
#pragma unroll
    for (int i = 0; i < 8; i++)
#pragma unroll
        for (int j = 0; j < 4; j++) acc[i][j] = (f32x4){0.f, 0.f, 0.f, 0.f};

    // prologue: stage K-tile 0 into buf 0
#pragma unroll
    for (int i = 0; i < 4; i++) { cp16(aptr[i], adst[i]); cp16(bptr[i], bdst[i]); }
    asm volatile("s_waitcnt vmcnt(0)" ::: "memory");
    __syncthreads();

    int cur = 0;
    for (int kt = 0; kt < HID / BK; kt++) {
        if (kt + 1 < HID / BK) {
            int kb = (kt + 1) * BK;
            int bo = (cur ^ 1) * LDSE;
#pragma unroll
            for (int i = 0; i < 4; i++) {
                cp16(aptr[i] + kb, adst[i] + bo);
                cp16(bptr[i] + kb, bdst[i] + bo);
            }
        }
        const u16* Ab = As[cur];
        const u16* Bb = Bs[cur];
#pragma unroll
        for (int ks = 0; ks < 2; ks++) {
            bf16x8 af[8], bfr[4];
            int q = ks * 4 + l4;
#pragma unroll
            for (int i = 0; i < 8; i++) {
                int ra = wm + i * 16 + l15;
                af[i] = *(const bf16x8*)&Ab[ra * BK + ((q ^ (ra & 7)) << 3)];
            }
#pragma unroll
            for (int j = 0; j < 4; j++) {
                int rb = wn + j * 16 + l15;
                bfr[j] = *(const bf16x8*)&Bb[rb * BK + ((q ^ (rb & 7)) << 3)];
            }
            __builtin_amdgcn_s_setprio(1);
#pragma unroll
            for (int i = 0; i < 8; i++)
#pragma unroll
                for (int j = 0; j < 4; j++)
                    acc[i][j] = __builtin_amdgcn_mfma_f32_16x16x32_bf16(bfr[j], af[i], acc[i][j], 0, 0, 0);
            __builtin_amdgcn_s_setprio(0);
        }
        if (kt + 1 < HID / BK) asm volatile("s_waitcnt vmcnt(0)" ::: "memory");
        __syncthreads();
        cur ^= 1;
    }

    int base_row = off[e] + mt * BM;
#pragma unroll
    for (int i = 0; i < 8; i++) {
        int m = wm + i * 16 + l15;
        int r = mt * BM + m;
        if (r < n_e) {
            u16* orow = hbuf + (size_t)(base_row + m) * HID2 + nt * BN + wn + l4 * 4;
#pragma unroll
            for (int j = 0; j < 4; j++) {
                u16 p[4];
#pragma unroll
                for (int rg = 0; rg < 4; rg++) p[rg] = f2bf(gelu_f(acc[i][j][rg]));
                *(uint2*)(orow + j * 16) = *(const uint2*)p;
            }
        }
    }
}

// ---------------- grouped GEMM2: ybuf = H @ W2t[e]^T (bf16, unweighted) ----
__global__ __launch_bounds__(512, 2) void gemm2_kernel(
    const u16* __restrict__ hbuf, const u16* __restrict__ w2t,
    const int* __restrict__ cntc, const int* __restrict__ off,
    const int* __restrict__ tmap, const int* __restrict__ ntile,
    u16* __restrict__ ybuf)
{
    __shared__ u16 As[2][LDSE];
    __shared__ u16 Bs[2][LDSE];

    int bt = blockIdx.x;
    if (bt >= ntile[0]) return;
    int em = tmap[bt];
    int e = em >> 16, mt = em & 0xffff;
    int nt = blockIdx.y;
    int n_e = cntc[e];

    int tid = threadIdx.x;
    int wv = tid >> 6, lane = tid & 63;
    int wm = (wv >> 2) * 128, wn = (wv & 3) * 64;
    int l15 = lane & 15, l4 = lane >> 4;
    int sr = lane >> 3, sc = lane & 7;

    const u16* hrow = hbuf + (size_t)(off[e] + mt * BM) * HID2;
    const u16* w2e = w2t + ((size_t)e * HID + nt * BN) * HID2;

    const u16* aptr[4]; const u16* bptr[4];
    u16* adst[4]; u16* bdst[4];
#pragma unroll
    for (int i = 0; i < 4; i++) {
        int m = wv * 32 + i * 8 + sr;
        int gq = sc ^ (m & 7);
        aptr[i] = hrow + (size_t)m * HID2 + gq * 8;
        adst[i] = &As[0][m * BK + sc * 8];
        bptr[i] = w2e + (size_t)m * HID2 + gq * 8;
        bdst[i] = &Bs[0][m * BK + sc * 8];
    }

    f32x4 acc[8][4];
#pragma unroll
    for (int i = 0; i < 8; i++)
#pragma unroll
        for (int j = 0; j < 4; j++) acc[i][j] = (f32x4){0.f, 0.f, 0.f, 0.f};

#pragma unroll
    for (int i = 0; i < 4; i++) { cp16(aptr[i], adst[i]); cp16(bptr[i], bdst[i]); }
    asm volatile("s_waitcnt vmcnt(0)" ::: "memory");
    __syncthreads();

    int cur = 0;
    for (int kt = 0; kt < HID2 / BK; kt++) {
        if (kt + 1 < HID2 / BK) {
            int kb = (kt + 1) * BK;
            int bo = (cur ^ 1) * LDSE;
#pragma unroll
            for (int i = 0; i < 4; i++) {
                cp16(aptr[i] + kb, adst[i] + bo);
                cp16(bptr[i] + kb, bdst[i] + bo);
            }
        }
        const u16* Ab = As[cur];
        const u16* Bb = Bs[cur];
#pragma unroll
        for (int ks = 0; ks < 2; ks++) {
            bf16x8 af[8], bfr[4];
            int q = ks * 4 + l4;
#pragma unroll
            for (int i = 0; i < 8; i++) {
                int ra = wm + i * 16 + l15;
                af[i] = *(const bf16x8*)&Ab[ra * BK + ((q ^ (ra & 7)) << 3)];
            }
#pragma unroll
            for (int j = 0; j < 4; j++) {
                int rb = wn + j * 16 + l15;
                bfr[j] = *(const bf16x8*)&Bb[rb * BK + ((q ^ (rb & 7)) << 3)];
            }
            __builtin_amdgcn_s_setprio(1);
#pragma unroll
            for (int i = 0; i < 8; i++)
#pragma unroll
                for (int j = 0; j < 4; j++)
                    acc[i][j] = __builtin_amdgcn_mfma_f32_16x16x32_bf16(bfr[j], af[i], acc[i][j], 0, 0, 0);
            __builtin_amdgcn_s_setprio(0);
        }
        if (kt + 1 < HID2 / BK) asm volatile("s_waitcnt vmcnt(0)" ::: "memory");
        __syncthreads();
        cur ^= 1;
    }

    int base_row = off[e] + mt * BM;
#pragma unroll
    for (int i = 0; i < 8; i++) {
        int m = wm + i * 16 + l15;
        int r = mt * BM + m;
        if (r < n_e) {
            u16* orow = ybuf + (size_t)(base_row + m) * HID + nt * BN + wn + l4 * 4;
#pragma unroll
            for (int j = 0; j < 4; j++) {
                u16 p[4];
#pragma unroll
                for (int rg = 0; rg < 4; rg++) p[rg] = f2bf(acc[i][j][rg]);
                *(uint2*)(orow + j * 16) = *(const uint2*)p;
            }
        }
    }
}

// ---------------- combine: out[t] = w0*y[r0] + w1*y[r1] ----------------
__global__ __launch_bounds__(256) void combine_kernel(
    const u16* __restrict__ ybuf, const int* __restrict__ off,
    const int* __restrict__ tok_slots, const float* __restrict__ tok_w,
    float* __restrict__ out)
{
    int tid = threadIdx.x;
    int t = blockIdx.x * 2 + (tid >> 7);
    int c = (tid & 127) * 8;
    int s0 = tok_slots[t * 2], s1 = tok_slots[t * 2 + 1];
    float w0 = tok_w[t * 2], w1 = tok_w[t * 2 + 1];
    int r0 = off[s0 >> 16] + (s0 & 0xFFFF);
    int r1 = off[s1 >> 16] + (s1 & 0xFFFF);
    uint4 a = *(const uint4*)(ybuf + (size_t)r0 * HID + c);
    uint4 b = *(const uint4*)(ybuf + (size_t)r1 * HID + c);
    const u16* pa = (const u16*)&a;
    const u16* pb = (const u16*)&b;
    float o[8];
#pragma unroll
    for (int q = 0; q < 8; q++) o[q] = w0 * bf2f(pa[q]) + w1 * bf2f(pb[q]);
    *(float4*)(out + (size_t)t * HID + c) = *(const float4*)&o[0];
    *(float4*)(out + (size_t)t * HID + c + 4) = *(const float4*)&o[4];
}

extern "C" void kernel_launch(void* const* d_in, const int* in_sizes, int n_in,
                              void* d_out, int out_size, void* d_ws, size_t ws_size,
                              hipStream_t stream)
{
    const float* x  = (const float*)d_in[0];   // [8192][1024] fp32
    const float* rw = (const float*)d_in[1];   // [8][1024] fp32
    const float* w1 = (const float*)d_in[2];   // [8][1024][2048] fp32
    const float* w2 = (const float*)d_in[3];   // [8][2048][1024] fp32
    float* out = (float*)d_out;                // [8192][1024] fp32

    // Workspace (~146 MiB): control | xb 16M | wt 32M | hbuf 64.5M | ybuf 32M
    char* ws = (char*)d_ws;
    int*   cnt       = (int*)(ws + 0);            // 8 counters, 128B apart (1 KiB)
    int*   off       = (int*)(ws + 1024);
    int*   cntc      = (int*)(ws + 1088);
    int*   tmap      = (int*)(ws + 1152);         // up to 72 tiles
    int*   ntile     = (int*)(ws + 1536);
    int*   rowlist   = (int*)(ws + 2048);                             // 256 KiB
    int*   tok_slots = (int*)(ws + 2048 + 262144);                    // 64 KiB
    float* tok_w     = (float*)(ws + 2048 + 262144 + 65536);          // 64 KiB
    u16*   xb        = (u16*)(ws + (1ull << 20));                     // 16 MiB
    u16*   wt        = (u16*)(ws + (17ull << 20));                    // 32 MiB
    u16*   hbuf      = (u16*)(ws + (49ull << 20));                    // 64.5 MiB
    u16*   ybuf      = (u16*)(ws + (114ull << 20));                   // 32 MiB

    hipMemsetAsync(cnt, 0, 1024, stream);

    router_kernel<<<T_TOKENS / 32, 256, 0, stream>>>(x, rw, xb, cnt, rowlist, tok_slots, tok_w);
    offsets_kernel<<<1, 64, 0, stream>>>(cnt, off, cntc, tmap, ntile);

    // w1 [E][1024][2048] -> wt [E][2048][1024]
    convtrans_kernel<<<dim3(HID2 / 64, HID / 64, NE), 256, 0, stream>>>(w1, wt, HID, HID2);
    gemm1_kernel<<<dim3(72, HID2 / BN, 1), 512, 0, stream>>>(xb, wt, cntc, off, rowlist, tmap, ntile, hbuf);

    // w2 [E][2048][1024] -> wt [E][1024][2048]
    convtrans_kernel<<<dim3(HID / 64, HID2 / 64, NE), 256, 0, stream>>>(w2, wt, HID2, HID);
    gemm2_kernel<<<dim3(72, HID / BN, 1), 512, 0, stream>>>(hbuf, wt, cntc, off, tmap, ntile, ybuf);

    combine_kernel<<<T_TOKENS / 2, 256, 0, stream>>>(ybuf, off, tok_slots, tok_w, out);
}

// Round 2
// 477.335 us; speedup vs baseline: 1.1480x; 1.0160x over previous
//
#include <hip/hip_runtime.h>
#include <cstdint>
#include <cstddef>

#define T_TOKENS 8192
#define HID 1024
#define HID2 2048
#define NE 8

typedef unsigned short u16;
typedef unsigned int u32;
typedef __bf16 bf16x8 __attribute__((ext_vector_type(8)));
typedef float f32x4 __attribute__((ext_vector_type(4)));

__device__ __forceinline__ float bf2f(u16 u) {
    union { u32 i; float f; } x; x.i = ((u32)u) << 16; return x.f;
}
__device__ __forceinline__ u16 f2bf(float f) {
    union { float f; u32 i; } x; x.f = f;
    u32 r = x.i + 0x7fffu + ((x.i >> 16) & 1u);   // RNE
    return (u16)(r >> 16);
}

// async 16B global -> LDS (lane-ordered dest: base + lane*16)
__device__ __forceinline__ void cp16(const void* g, void* l) {
    __builtin_amdgcn_global_load_lds(
        (const __attribute__((address_space(1))) u32*)g,
        (__attribute__((address_space(3))) u32*)l,
        16, 0, 0);
}

// tanh-approx GELU: |err| < ~3e-4, buried under bf16 rounding
__device__ __forceinline__ float gelu_f(float v) {
    float v2 = v * v;
    float t = fmaf(0.0713548162726f, v2, 1.59576912161f);
    float d = 1.0f + __expf(-v * t);
    return v * __builtin_amdgcn_rcpf(d);
}

#define BAR()   asm volatile("s_barrier" ::: "memory")
#define LGKM0() asm volatile("s_waitcnt lgkmcnt(0)" ::: "memory")
#define VMC(n)  asm volatile("s_waitcnt vmcnt(" #n ")" ::: "memory")

// slot swizzle: 2 lanes per (parity,slot) group -> uniform 8 accesses/bank on b128
__device__ __forceinline__ int sfun(int r) { return (r & 2) | ((r >> 2) & 1); }

// ---------------- router: 8 tokens/wave, fused x->bf16 convert ----------------
__global__ __launch_bounds__(256) void router_kernel(
    const float* __restrict__ x, const float* __restrict__ rw,
    u16* __restrict__ xb,
    int* __restrict__ cnt, int* __restrict__ rowlist,
    int* __restrict__ tok_slots, float* __restrict__ tok_w)
{
    __shared__ int lbin[NE];
    __shared__ int gbase[NE];
    int tid = threadIdx.x;
    if (tid < NE) lbin[tid] = 0;
    __syncthreads();

    int wave = tid >> 6;
    int lane = tid & 63;
    int tg = lane >> 3, il = lane & 7;
    int t = blockIdx.x * 32 + wave * 8 + tg;

    const float* xrow = x + (size_t)t * HID;
    u16* xbrow = xb + (size_t)t * HID;

    float acc[NE];
#pragma unroll
    for (int e = 0; e < NE; e++) acc[e] = 0.f;

#pragma unroll 8
    for (int q = 0; q < 32; q++) {
        int c = il * 4 + 32 * q;
        float4 xv = *(const float4*)(xrow + c);
        u16 p[4] = { f2bf(xv.x), f2bf(xv.y), f2bf(xv.z), f2bf(xv.w) };
        *(uint2*)(xbrow + c) = *(const uint2*)p;
#pragma unroll
        for (int e = 0; e < NE; e++) {
            float4 rv = *(const float4*)(rw + (size_t)e * HID + c);
            acc[e] = fmaf(xv.x, rv.x, acc[e]);
            acc[e] = fmaf(xv.y, rv.y, acc[e]);
            acc[e] = fmaf(xv.z, rv.z, acc[e]);
            acc[e] = fmaf(xv.w, rv.w, acc[e]);
        }
    }
#pragma unroll
    for (int e = 0; e < NE; e++) {
        acc[e] += __shfl_xor(acc[e], 1, 64);
        acc[e] += __shfl_xor(acc[e], 2, 64);
        acc[e] += __shfl_xor(acc[e], 4, 64);
    }

    int i0 = 0, i1 = 0, ph0 = 0, ph1 = 0;
    float w0 = 0.f, w1 = 0.f;
    if (il == 0) {
        float v0 = -1e30f;
#pragma unroll
        for (int e = 0; e < NE; e++) if (acc[e] > v0) { v0 = acc[e]; i0 = e; }
        float v1 = -1e30f;
#pragma unroll
        for (int e = 0; e < NE; e++) if (e != i0 && acc[e] > v1) { v1 = acc[e]; i1 = e; }
        w0 = 1.0f / (1.0f + __expf(v1 - v0));
        w1 = 1.0f - w0;
        ph0 = atomicAdd(&lbin[i0], 1);
        ph1 = atomicAdd(&lbin[i1], 1);
    }
    __syncthreads();
    if (tid < NE) gbase[tid] = atomicAdd(&cnt[tid * 32], lbin[tid]);
    __syncthreads();
    if (il == 0) {
        int p0 = gbase[i0] + ph0;
        int p1 = gbase[i1] + ph1;
        rowlist[i0 * T_TOKENS + p0] = t;
        rowlist[i1 * T_TOKENS + p1] = t;
        tok_slots[t * 2 + 0] = (i0 << 16) | p0;
        tok_slots[t * 2 + 1] = (i1 << 16) | p1;
        tok_w[t * 2 + 0] = w0;
        tok_w[t * 2 + 1] = w1;
    }
}

#define BM 256
#define BN 256
#define BK 64
#define HLF 8192   // u16 elements per (buf, khalf) region: 256 rows * 32

// ------- offsets: scan + compact + tile map (skip no-op blocks) -------
__global__ void offsets_kernel(const int* __restrict__ cnt,
                               int* __restrict__ off, int* __restrict__ cntc,
                               int* __restrict__ tmap, int* __restrict__ ntile)
{
    if (threadIdx.x == 0) {
        int s = 0, ti = 0;
        for (int e = 0; e < NE; e++) {
            int c = cnt[e * 32];
            off[e] = s; cntc[e] = c; s += c;
            int nmt = (c + BM - 1) / BM;
            for (int m = 0; m < nmt; m++) tmap[ti++] = (e << 16) | m;
        }
        ntile[0] = ti;
    }
}

// ------- convert+transpose: fp32 [E][K][N] -> bf16 [E][N][K] -------
__global__ __launch_bounds__(256) void convtrans_kernel(
    const float* __restrict__ in, u16* __restrict__ outp, int K, int N)
{
    __shared__ u16 tile[64][72];
    int e = blockIdx.z;
    const float* ip = in + (size_t)e * K * N;
    u16* op = outp + (size_t)e * K * N;
    int n0 = blockIdx.x * 64, k0 = blockIdx.y * 64;
    int t = threadIdx.x;

    int k = t >> 2;
    int nq = (t & 3) * 16;
    const float* src = ip + (size_t)(k0 + k) * N + n0 + nq;
#pragma unroll
    for (int q = 0; q < 4; q++) {
        float4 v = *(const float4*)(src + q * 4);
        tile[nq + q * 4 + 0][k] = f2bf(v.x);
        tile[nq + q * 4 + 1][k] = f2bf(v.y);
        tile[nq + q * 4 + 2][k] = f2bf(v.z);
        tile[nq + q * 4 + 3][k] = f2bf(v.w);
    }
    __syncthreads();

    int n = t >> 2;
    int kq = (t & 3) * 16;
    u16* dst = op + (size_t)(n0 + n) * K + k0 + kq;
    *(uint4*)(dst + 0) = *(const uint4*)&tile[n][kq + 0];
    *(uint4*)(dst + 8) = *(const uint4*)&tile[n][kq + 8];
}

// ---------------- grouped GEMM1: h = gelu(X_gather @ W1t[e]^T) ----------------
// 256x256x64, 8 waves, 4-phase/K-tile pipelined schedule with counted vmcnt.
// LDS per matrix: [2 buf][2 khalf][256 r][4 slots*16B], slot=(k8&3)^sfun(r).
// Stage ledger per tile t: ph0 A_k1(t+1), ph1 B_k1(t+1), ph2 A_k0(t+2),
// ph3 B_k0(t+2) + vmcnt(4) -> tile t+1 fully resident, 2 half-tiles in flight.
__global__ __launch_bounds__(512, 2) void gemm1_kernel(
    const u16* __restrict__ xb, const u16* __restrict__ w1t,
    const int* __restrict__ cntc, const int* __restrict__ off,
    const int* __restrict__ rowlist, const int* __restrict__ tmap,
    const int* __restrict__ ntile, u16* __restrict__ hbuf)
{
    __shared__ u16 AsF[4 * HLF];
    __shared__ u16 BsF[4 * HLF];
    __shared__ int toks[BM];

    int id = blockIdx.x;
    int swz = (id & 7) * 72 + (id >> 3);    // 576 blocks, XCD-chunked
    int bt = swz >> 3, nt = swz & 7;
    if (bt >= ntile[0]) return;
    int em = tmap[bt];
    int e = em >> 16, mt = em & 0xffff;
    int n_e = cntc[e];

    int tid = threadIdx.x;
    if (tid < BM) {
        int r = mt * BM + tid;
        if (r >= n_e) r = n_e - 1;          // clamp: duplicate last valid row
        toks[tid] = rowlist[e * T_TOKENS + r];
    }
    __syncthreads();

    int wv = tid >> 6, lane = tid & 63;
    int wm = (wv >> 2) * 128, wn = (wv & 3) * 64;
    int l15 = lane & 15, l4 = lane >> 4;

    // staging geometry: per thread 2 rows (r0,r1), 1 slot each, per half-tile
    int r0 = (wv * 2 + 0) * 16 + (lane >> 2);
    int r1 = (wv * 2 + 1) * 16 + (lane >> 2);
    int sl = lane & 3;
    int as0 = (sl ^ sfun(r0)) << 3;
    int as1 = (sl ^ sfun(r1)) << 3;
    int d0 = (wv * 2 + 0) * 512 + lane * 8;
    int d1 = (wv * 2 + 1) * 512 + lane * 8;
    const u16* aRow0 = xb + (size_t)toks[r0] * HID;
    const u16* aRow1 = xb + (size_t)toks[r1] * HID;
    const u16* w1e = w1t + ((size_t)e * HID2 + (size_t)nt * BN) * HID;
    const u16* bRow0 = w1e + (size_t)r0 * HID;
    const u16* bRow1 = w1e + (size_t)r1 * HID;

    // fragment read offsets (within a (buf,khalf) region)
    int aoff[8], boff[4];
#pragma unroll
    for (int i = 0; i < 8; i++) { int ra = wm + i * 16 + l15; aoff[i] = ra * 32 + ((l4 ^ sfun(ra)) << 3); }
#pragma unroll
    for (int j = 0; j < 4; j++) { int rb = wn + j * 16 + l15; boff[j] = rb * 32 + ((l4 ^ sfun(rb)) << 3); }

    f32x4 acc[8][4];
#pragma unroll
    for (int i = 0; i < 8; i++)
#pragma unroll
        for (int j = 0; j < 4; j++) acc[i][j] = (f32x4){0.f, 0.f, 0.f, 0.f};

#define ST_A(db, h, kt) do { \
    cp16(aRow0 + (kt) * BK + (h) * 32 + as0, &AsF[((db) * 2 + (h)) * HLF + d0]); \
    cp16(aRow1 + (kt) * BK + (h) * 32 + as1, &AsF[((db) * 2 + (h)) * HLF + d1]); } while (0)
#define ST_B(db, h, kt) do { \
    cp16(bRow0 + (kt) * BK + (h) * 32 + as0, &BsF[((db) * 2 + (h)) * HLF + d0]); \
    cp16(bRow1 + (kt) * BK + (h) * 32 + as1, &BsF[((db) * 2 + (h)) * HLF + d1]); } while (0)

    const int NKT = HID / BK;   // 16
    // prologue: tile0 all 4 halves + tile1 k0 halves (12 loads/thread)
    ST_A(0, 0, 0); ST_B(0, 0, 0);
    ST_A(0, 1, 0); ST_B(0, 1, 0);
    ST_A(1, 0, 1); ST_B(1, 0, 1);
    VMC(4);
    BAR();

    for (int kt = 0; kt < NKT; kt++) {
        int buf = kt & 1, nbuf = buf ^ 1;
        int base0 = (buf * 2 + 0) * HLF;
        int base1 = (buf * 2 + 1) * HLF;
        bf16x8 af[8], bq0, bq1;
        // ---- ph0: ks0, n-frags 0/1 ----
#pragma unroll
        for (int i = 0; i < 8; i++) af[i] = *(const bf16x8*)&AsF[base0 + aoff[i]];
        bq0 = *(const bf16x8*)&BsF[base0 + boff[0]];
        bq1 = *(const bf16x8*)&BsF[base0 + boff[1]];
        if (kt + 1 < NKT) ST_A(nbuf, 1, kt + 1);
        BAR(); LGKM0();
        __builtin_amdgcn_s_setprio(1);
#pragma unroll
        for (int i = 0; i < 8; i++) {
            acc[i][0] = __builtin_amdgcn_mfma_f32_16x16x32_bf16(bq0, af[i], acc[i][0], 0, 0, 0);
            acc[i][1] = __builtin_amdgcn_mfma_f32_16x16x32_bf16(bq1, af[i], acc[i][1], 0, 0, 0);
        }
        __builtin_amdgcn_s_setprio(0);
        BAR();
        // ---- ph1: ks0, n-frags 2/3 (A-frags reused from regs) ----
        bq0 = *(const bf16x8*)&BsF[base0 + boff[2]];
        bq1 = *(const bf16x8*)&BsF[base0 + boff[3]];
        if (kt + 1 < NKT) ST_B(nbuf, 1, kt + 1);
        BAR(); LGKM0();
        __builtin_amdgcn_s_setprio(1);
#pragma unroll
        for (int i = 0; i < 8; i++) {
            acc[i][2] = __builtin_amdgcn_mfma_f32_16x16x32_bf16(bq0, af[i], acc[i][2], 0, 0, 0);
            acc[i][3] = __builtin_amdgcn_mfma_f32_16x16x32_bf16(bq1, af[i], acc[i][3], 0, 0, 0);
        }
        __builtin_amdgcn_s_setprio(0);
        BAR();
        // ---- ph2: ks1, n-frags 0/1 ----
#pragma unroll
        for (int i = 0; i < 8; i++) af[i] = *(const bf16x8*)&AsF[base1 + aoff[i]];
        bq0 = *(const bf16x8*)&BsF[base1 + boff[0]];
        bq1 = *(const bf16x8*)&BsF[base1 + boff[1]];
        if (kt + 2 < NKT) ST_A(buf, 0, kt + 2);
        BAR(); LGKM0();
        __builtin_amdgcn_s_setprio(1);
#pragma unroll
        for (int i = 0; i < 8; i++) {
            acc[i][0] = __builtin_amdgcn_mfma_f32_16x16x32_bf16(bq0, af[i], acc[i][0], 0, 0, 0);
            acc[i][1] = __builtin_amdgcn_mfma_f32_16x16x32_bf16(bq1, af[i], acc[i][1], 0, 0, 0);
        }
        __builtin_amdgcn_s_setprio(0);
        BAR();
        // ---- ph3: ks1, n-frags 2/3 ----
        bq0 = *(const bf16x8*)&BsF[base1 + boff[2]];
        bq1 = *(const bf16x8*)&BsF[base1 + boff[3]];
        if (kt + 2 < NKT) ST_B(buf, 0, kt + 2);
        BAR(); LGKM0();
        __builtin_amdgcn_s_setprio(1);
#pragma unroll
        for (int i = 0; i < 8; i++) {
            acc[i][2] = __builtin_amdgcn_mfma_f32_16x16x32_bf16(bq0, af[i], acc[i][2], 0, 0, 0);
            acc[i][3] = __builtin_amdgcn_mfma_f32_16x16x32_bf16(bq1, af[i], acc[i][3], 0, 0, 0);
        }
        __builtin_amdgcn_s_setprio(0);
        if (kt + 2 < NKT)      { VMC(4); }
        else if (kt + 1 < NKT) { VMC(0); }
        BAR();
    }
#undef ST_A
#undef ST_B

    int base_row = off[e] + mt * BM;
#pragma unroll
    for (int i = 0; i < 8; i++) {
        int m = wm + i * 16 + l15;
        int r = mt * BM + m;
        if (r < n_e) {
            u16* orow = hbuf + (size_t)(base_row + m) * HID2 + nt * BN + wn + l4 * 4;
#pragma unroll
            for (int j = 0; j < 4; j++) {
                u16 p[4];
#pragma unroll
                for (int rg = 0; rg < 4; rg++) p[rg] = f2bf(gelu_f(acc[i][j][rg]));
                *(uint2*)(orow + j * 16) = *(const uint2*)p;
            }
        }
    }
}

// ---------------- grouped GEMM2: ybuf = H @ W2t[e]^T (bf16, unweighted) ----
__global__ __launch_bounds__(512, 2) void gemm2_kernel(
    const u16* __restrict__ hbuf, const u16* __restrict__ w2t,
    const int* __restrict__ cntc, const int* __restrict__ off,
    const int* __restrict__ tmap, const int* __restrict__ ntile,
    u16* __restrict__ ybuf)
{
    __shared__ u16 AsF[4 * HLF];
    __shared__ u16 BsF[4 * HLF];

    int id = blockIdx.x;
    int swz = (id & 7) * 36 + (id >> 3);    // 288 blocks, XCD-chunked
    int bt = swz >> 2, nt = swz & 3;
    if (bt >= ntile[0]) return;
    int em = tmap[bt];
    int e = em >> 16, mt = em & 0xffff;
    int n_e = cntc[e];

    int tid = threadIdx.x;
    int wv = tid >> 6, lane = tid & 63;
    int wm = (wv >> 2) * 128, wn = (wv & 3) * 64;
    int l15 = lane & 15, l4 = lane >> 4;

    int r0 = (wv * 2 + 0) * 16 + (lane >> 2);
    int r1 = (wv * 2 + 1) * 16 + (lane >> 2);
    int sl = lane & 3;
    int as0 = (sl ^ sfun(r0)) << 3;
    int as1 = (sl ^ sfun(r1)) << 3;
    int d0 = (wv * 2 + 0) * 512 + lane * 8;
    int d1 = (wv * 2 + 1) * 512 + lane * 8;
    const u16* hrow = hbuf + (size_t)(off[e] + mt * BM) * HID2;
    const u16* aRow0 = hrow + (size_t)r0 * HID2;
    const u16* aRow1 = hrow + (size_t)r1 * HID2;
    const u16* w2e = w2t + ((size_t)e * HID + (size_t)nt * BN) * HID2;
    const u16* bRow0 = w2e + (size_t)r0 * HID2;
    const u16* bRow1 = w2e + (size_t)r1 * HID2;

    int aoff[8], boff[4];
#pragma unroll
    for (int i = 0; i < 8; i++) { int ra = wm + i * 16 + l15; aoff[i] = ra * 32 + ((l4 ^ sfun(ra)) << 3); }
#pragma unroll
    for (int j = 0; j < 4; j++) { int rb = wn + j * 16 + l15; boff[j] = rb * 32 + ((l4 ^ sfun(rb)) << 3); }

    f32x4 acc[8][4];
#pragma unroll
    for (int i = 0; i < 8; i++)
#pragma unroll
        for (int j = 0; j < 4; j++) acc[i][j] = (f32x4){0.f, 0.f, 0.f, 0.f};

#define ST_A(db, h, kt) do { \
    cp16(aRow0 + (kt) * BK + (h) * 32 + as0, &AsF[((db) * 2 + (h)) * HLF + d0]); \
    cp16(aRow1 + (kt) * BK + (h) * 32 + as1, &AsF[((db) * 2 + (h)) * HLF + d1]); } while (0)
#define ST_B(db, h, kt) do { \
    cp16(bRow0 + (kt) * BK + (h) * 32 + as0, &BsF[((db) * 2 + (h)) * HLF + d0]); \
    cp16(bRow1 + (kt) * BK + (h) * 32 + as1, &BsF[((db) * 2 + (h)) * HLF + d1]); } while (0)

    const int NKT = HID2 / BK;  // 32
    ST_A(0, 0, 0); ST_B(0, 0, 0);
    ST_A(0, 1, 0); ST_B(0, 1, 0);
    ST_A(1, 0, 1); ST_B(1, 0, 1);
    VMC(4);
    BAR();

    for (int kt = 0; kt < NKT; kt++) {
        int buf = kt & 1, nbuf = buf ^ 1;
        int base0 = (buf * 2 + 0) * HLF;
        int base1 = (buf * 2 + 1) * HLF;
        bf16x8 af[8], bq0, bq1;
        // ---- ph0 ----
#pragma unroll
        for (int i = 0; i < 8; i++) af[i] = *(const bf16x8*)&AsF[base0 + aoff[i]];
        bq0 = *(const bf16x8*)&BsF[base0 + boff[0]];
        bq1 = *(const bf16x8*)&BsF[base0 + boff[1]];
        if (kt + 1 < NKT) ST_A(nbuf, 1, kt + 1);
        BAR(); LGKM0();
        __builtin_amdgcn_s_setprio(1);
#pragma unroll
        for (int i = 0; i < 8; i++) {
            acc[i][0] = __builtin_amdgcn_mfma_f32_16x16x32_bf16(bq0, af[i], acc[i][0], 0, 0, 0);
            acc[i][1] = __builtin_amdgcn_mfma_f32_16x16x32_bf16(bq1, af[i], acc[i][1], 0, 0, 0);
        }
        __builtin_amdgcn_s_setprio(0);
        BAR();
        // ---- ph1 ----
        bq0 = *(const bf16x8*)&BsF[base0 + boff[2]];
        bq1 = *(const bf16x8*)&BsF[base0 + boff[3]];
        if (kt + 1 < NKT) ST_B(nbuf, 1, kt + 1);
        BAR(); LGKM0();
        __builtin_amdgcn_s_setprio(1);
#pragma unroll
        for (int i = 0; i < 8; i++) {
            acc[i][2] = __builtin_amdgcn_mfma_f32_16x16x32_bf16(bq0, af[i], acc[i][2], 0, 0, 0);
            acc[i][3] = __builtin_amdgcn_mfma_f32_16x16x32_bf16(bq1, af[i], acc[i][3], 0, 0, 0);
        }
        __builtin_amdgcn_s_setprio(0);
        BAR();
        // ---- ph2 ----
#pragma unroll
        for (int i = 0; i < 8; i++) af[i] = *(const bf16x8*)&AsF[base1 + aoff[i]];
        bq0 = *(const bf16x8*)&BsF[base1 + boff[0]];
        bq1 = *(const bf16x8*)&BsF[base1 + boff[1]];
        if (kt + 2 < NKT) ST_A(buf, 0, kt + 2);
        BAR(); LGKM0();
        __builtin_amdgcn_s_setprio(1);
#pragma unroll
        for (int i = 0; i < 8; i++) {
            acc[i][0] = __builtin_amdgcn_mfma_f32_16x16x32_bf16(bq0, af[i], acc[i][0], 0, 0, 0);
            acc[i][1] = __builtin_amdgcn_mfma_f32_16x16x32_bf16(bq1, af[i], acc[i][1], 0, 0, 0);
        }
        __builtin_amdgcn_s_setprio(0);
        BAR();
        // ---- ph3 ----
        bq0 = *(const bf16x8*)&BsF[base1 + boff[2]];
        bq1 = *(const bf16x8*)&BsF[base1 + boff[3]];
        if (kt + 2 < NKT) ST_B(buf, 0, kt + 2);
        BAR(); LGKM0();
        __builtin_amdgcn_s_setprio(1);
#pragma unroll
        for (int i = 0; i < 8; i++) {
            acc[i][2] = __builtin_amdgcn_mfma_f32_16x16x32_bf16(bq0, af[i], acc[i][2], 0, 0, 0);
            acc[i][3] = __builtin_amdgcn_mfma_f32_16x16x32_bf16(bq1, af[i], acc[i][3], 0, 0, 0);
        }
        __builtin_amdgcn_s_setprio(0);
        if (kt + 2 < NKT)      { VMC(4); }
        else if (kt + 1 < NKT) { VMC(0); }
        BAR();
    }
#undef ST_A
#undef ST_B

    int base_row = off[e] + mt * BM;
#pragma unroll
    for (int i = 0; i < 8; i++) {
        int m = wm + i * 16 + l15;
        int r = mt * BM + m;
        if (r < n_e) {
            u16* orow = ybuf + (size_t)(base_row + m) * HID + nt * BN + wn + l4 * 4;
#pragma unroll
            for (int j = 0; j < 4; j++) {
                u16 p[4];
#pragma unroll
                for (int rg = 0; rg < 4; rg++) p[rg] = f2bf(acc[i][j][rg]);
                *(uint2*)(orow + j * 16) = *(const uint2*)p;
            }
        }
    }
}

// ---------------- combine: out[t] = w0*y[r0] + w1*y[r1] ----------------
__global__ __launch_bounds__(256) void combine_kernel(
    const u16* __restrict__ ybuf, const int* __restrict__ off,
    const int* __restrict__ tok_slots, const float* __restrict__ tok_w,
    float* __restrict__ out)
{
    int tid = threadIdx.x;
    int t = blockIdx.x * 2 + (tid >> 7);
    int c = (tid & 127) * 8;
    int s0 = tok_slots[t * 2], s1 = tok_slots[t * 2 + 1];
    float w0 = tok_w[t * 2], w1 = tok_w[t * 2 + 1];
    int r0 = off[s0 >> 16] + (s0 & 0xFFFF);
    int r1 = off[s1 >> 16] + (s1 & 0xFFFF);
    uint4 a = *(const uint4*)(ybuf + (size_t)r0 * HID + c);
    uint4 b = *(const uint4*)(ybuf + (size_t)r1 * HID + c);
    const u16* pa = (const u16*)&a;
    const u16* pb = (const u16*)&b;
    float o[8];
#pragma unroll
    for (int q = 0; q < 8; q++) o[q] = w0 * bf2f(pa[q]) + w1 * bf2f(pb[q]);
    *(float4*)(out + (size_t)t * HID + c) = *(const float4*)&o[0];
    *(float4*)(out + (size_t)t * HID + c + 4) = *(const float4*)&o[4];
}

extern "C" void kernel_launch(void* const* d_in, const int* in_sizes, int n_in,
                              void* d_out, int out_size, void* d_ws, size_t ws_size,
                              hipStream_t stream)
{
    const float* x  = (const float*)d_in[0];   // [8192][1024] fp32
    const float* rw = (const float*)d_in[1];   // [8][1024] fp32
    const float* w1 = (const float*)d_in[2];   // [8][1024][2048] fp32
    const float* w2 = (const float*)d_in[3];   // [8][2048][1024] fp32
    float* out = (float*)d_out;                // [8192][1024] fp32

    // Workspace (~146 MiB): control | xb 16M | wt 32M | hbuf 64.5M | ybuf 32M
    char* ws = (char*)d_ws;
    int*   cnt       = (int*)(ws + 0);            // 8 counters, 128B apart (1 KiB)
    int*   off       = (int*)(ws + 1024);
    int*   cntc      = (int*)(ws + 1088);
    int*   tmap      = (int*)(ws + 1152);         // up to 72 tiles
    int*   ntile     = (int*)(ws + 1536);
    int*   rowlist   = (int*)(ws + 2048);                             // 256 KiB
    int*   tok_slots = (int*)(ws + 2048 + 262144);                    // 64 KiB
    float* tok_w     = (float*)(ws + 2048 + 262144 + 65536);          // 64 KiB
    u16*   xb        = (u16*)(ws + (1ull << 20));                     // 16 MiB
    u16*   wt        = (u16*)(ws + (17ull << 20));                    // 32 MiB
    u16*   hbuf      = (u16*)(ws + (49ull << 20));                    // 64.5 MiB
    u16*   ybuf      = (u16*)(ws + (114ull << 20));                   // 32 MiB

    hipMemsetAsync(cnt, 0, 1024, stream);

    router_kernel<<<T_TOKENS / 32, 256, 0, stream>>>(x, rw, xb, cnt, rowlist, tok_slots, tok_w);
    offsets_kernel<<<1, 64, 0, stream>>>(cnt, off, cntc, tmap, ntile);

    // w1 [E][1024][2048] -> wt [E][2048][1024]
    convtrans_kernel<<<dim3(HID2 / 64, HID / 64, NE), 256, 0, stream>>>(w1, wt, HID, HID2);
    gemm1_kernel<<<72 * (HID2 / BN), 512, 0, stream>>>(xb, wt, cntc, off, rowlist, tmap, ntile, hbuf);

    // w2 [E][2048][1024] -> wt [E][1024][2048]
    convtrans_kernel<<<dim3(HID / 64, HID2 / 64, NE), 256, 0, stream>>>(w2, wt, HID2, HID);
    gemm2_kernel<<<72 * (HID / BN), 512, 0, stream>>>(hbuf, wt, cntc, off, tmap, ntile, ybuf);

    combine_kernel<<<T_TOKENS / 2, 256, 0, stream>>>(ybuf, off, tok_slots, tok_w, out);
}